// Round 7
// baseline (1213.841 us; speedup 1.0000x reference)
//
#include <hip/hip_runtime.h>

#define D 128

// ---------------- preprocessing ----------------

__global__ void k_count(const int* __restrict__ dst, int* __restrict__ deg, int E) {
    int e = blockIdx.x * 256 + threadIdx.x;
    if (e < E) atomicAdd(&deg[dst[e]], 1);
}

__global__ __launch_bounds__(256) void k_blocksum(const int* __restrict__ deg,
                                                  int* __restrict__ bsums, int N) {
    __shared__ int s[256];
    int base = blockIdx.x * 1024 + threadIdx.x * 4;
    int v = 0;
#pragma unroll
    for (int j = 0; j < 4; ++j) { int i = base + j; if (i < N) v += deg[i]; }
    s[threadIdx.x] = v;
    __syncthreads();
    for (int off = 128; off > 0; off >>= 1) {
        if (threadIdx.x < off) s[threadIdx.x] += s[threadIdx.x + off];
        __syncthreads();
    }
    if (threadIdx.x == 0) bsums[blockIdx.x] = s[0];
}

__global__ __launch_bounds__(256) void k_scanbsums(int* __restrict__ bsums, int NB) {
    __shared__ int s[256];
    __shared__ int carry;
    int t = threadIdx.x;
    if (t == 0) carry = 0;
    __syncthreads();
    for (int base = 0; base < NB; base += 256) {
        int i = base + t;
        int v = (i < NB) ? bsums[i] : 0;
        s[t] = v;
        __syncthreads();
        for (int off = 1; off < 256; off <<= 1) {
            int x = (t >= off) ? s[t - off] : 0;
            __syncthreads();
            s[t] += x;
            __syncthreads();
        }
        if (i < NB) bsums[i] = carry + s[t] - v;   // exclusive
        __syncthreads();
        if (t == 0) carry += s[255];
        __syncthreads();
    }
}

__global__ __launch_bounds__(256) void k_scan2(const int* __restrict__ deg,
                                               const int* __restrict__ bsums,
                                               int* __restrict__ rowst,
                                               float* __restrict__ dinv, int N) {
    __shared__ int s[256];
    int t = threadIdx.x;
    int base = blockIdx.x * 1024 + t * 4;
    int v[4];
#pragma unroll
    for (int j = 0; j < 4; ++j) { int i = base + j; v[j] = (i < N) ? deg[i] : 0; }
    int tsum = v[0] + v[1] + v[2] + v[3];
    s[t] = tsum;
    __syncthreads();
    for (int off = 1; off < 256; off <<= 1) {
        int x = (t >= off) ? s[t - off] : 0;
        __syncthreads();
        s[t] += x;
        __syncthreads();
    }
    int run = s[t] - tsum + bsums[blockIdx.x];
#pragma unroll
    for (int j = 0; j < 4; ++j) {
        int i = base + j;
        if (i < N) {
            rowst[i] = run;
            dinv[i] = rsqrtf((float)(v[j] + 1));   // +1 for self-loop
        }
        run += v[j];
    }
}

// csr entry: .x = src node, .y = bitcast f32 edge weight
__global__ void k_fill(const int* __restrict__ src, const int* __restrict__ dst,
                       const int* __restrict__ rowst, int* __restrict__ cursor,
                       const float* __restrict__ dinv, int2* __restrict__ csr, int E) {
    int e = blockIdx.x * 256 + threadIdx.x;
    if (e >= E) return;
    int s = src[e], d = dst[e];
    int p = rowst[d] + atomicAdd(&cursor[d], 1);
    csr[p] = make_int2(s, __float_as_int(dinv[s] * dinv[d]));
}

// ---------------- f32 GEMM: Out[M,128] = A[M,128] @ W[128,128] ----------------
// Wave-mapping v3: per wave 8 rows x 128 cols, 2 cols/lane.
//  - W read: 1 ds_read_b64 per k for 16 FMAs/thread = 0.5 LDS-B/lane-FMA
//    (R2's pattern was 1.0 -> capped at ~66% VALU by the 85 B/cyc LDS pipe).
//    16-lane phases hit 32 distinct banks: conflict-free.
//  - A read: lane-identical LDS broadcasts (conflict-free; DS can't be
//    scalarized -> avoids R5's s_load/lgkmcnt entanglement).
//  - acc float2[8]=16 VGPR, a[8] f4=32 -> ~80 VGPR, no spill (R3/R4 trap).
//  - 32 rows/block, grid 3125 (12.2/CU), LDS 40.5 KB -> 3 blocks/CU,
//    BK=64 -> 4 barriers total. NO launch_bounds min-waves arg.

__global__ __launch_bounds__(256) void k_gemm128(const float* __restrict__ A,
                                                 const float* __restrict__ W,
                                                 float* __restrict__ Out, int M) {
    __shared__ float sW[64][D];     // 32 KB, one 64-k slice of W
    __shared__ float sA[32][68];    // 8.5 KB, [row][k] within slice (pad 4)
    const int t = threadIdx.x;
    const int row0 = blockIdx.x * 32;
    const int lane = t & 63;
    const int wv = t >> 6;          // wave 0..3 -> rows wv*8..wv*8+7

    float2 acc[8];
#pragma unroll
    for (int r = 0; r < 8; ++r) acc[r] = make_float2(0.f, 0.f);

    for (int kt = 0; kt < D; kt += 64) {
        __syncthreads();   // protect previous iteration's reads (no-op cost on iter 0)
        // stage A slice: 32 rows x 64 k = 512 float4s; 2 per thread
#pragma unroll
        for (int p = 0; p < 2; ++p) {
            int idx = t + 256 * p;
            int row = idx >> 4, kq = idx & 15;
            int grow = row0 + row; if (grow > M - 1) grow = M - 1;
            *(float4*)&sA[row][kq * 4] = *(const float4*)&A[(size_t)grow * D + kt + kq * 4];
        }
        // stage W slice: 64 k x 128 cols = 2048 float4s; 8 per thread
#pragma unroll
        for (int p = 0; p < 8; ++p) {
            int idx = t + 256 * p;
            int wr = idx >> 5, wc = idx & 31;
            *(float4*)&sW[wr][wc * 4] = *(const float4*)&W[(size_t)(kt + wr) * D + wc * 4];
        }
        __syncthreads();

#pragma unroll 4
        for (int k4 = 0; k4 < 16; ++k4) {
            float4 a[8];
#pragma unroll
            for (int r = 0; r < 8; ++r)
                a[r] = *(const float4*)&sA[wv * 8 + r][k4 * 4];   // broadcast
#pragma unroll
            for (int j = 0; j < 4; ++j) {
                float2 w2 = *(const float2*)&sW[k4 * 4 + j][lane * 2];
                const float* ap;
#pragma unroll
                for (int r = 0; r < 8; ++r) {
                    ap = (const float*)&a[r];
                    acc[r].x = fmaf(ap[j], w2.x, acc[r].x);
                    acc[r].y = fmaf(ap[j], w2.y, acc[r].y);
                }
            }
        }
    }

#pragma unroll
    for (int r = 0; r < 8; ++r) {
        int grow = row0 + wv * 8 + r;
        if (grow < M)
            *(float2*)&Out[(size_t)grow * D + lane * 2] = acc[r];
    }
}

// ---------------- aggregation ----------------
// Round-2 exact (nt-store experiment reverted: it cost ~5 us/dispatch in R6).

__global__ __launch_bounds__(256) void k_aggr(const float* __restrict__ T,
                                              const int2* __restrict__ csr,
                                              const int* __restrict__ rowst,
                                              const int* __restrict__ deg,
                                              const float* __restrict__ dinv,
                                              const float* __restrict__ bias,
                                              float* __restrict__ Hout, int N, int relu) {
    int node = blockIdx.x * 8 + (threadIdx.x >> 5);
    if (node >= N) return;
    int c = (threadIdx.x & 31) << 2;
    float di = dinv[node];
    float s2 = di * di;
    float4 t0 = *(const float4*)&T[(size_t)node * D + c];
    float4 bv = *(const float4*)&bias[c];
    float4 acc;
    acc.x = fmaf(s2, t0.x, bv.x);
    acc.y = fmaf(s2, t0.y, bv.y);
    acc.z = fmaf(s2, t0.z, bv.z);
    acc.w = fmaf(s2, t0.w, bv.w);

    int s0 = rowst[node];
    int cnt = deg[node];
    int j = 0;
    for (; j + 4 <= cnt; j += 4) {
        int2 e0 = csr[s0 + j + 0];
        int2 e1 = csr[s0 + j + 1];
        int2 e2 = csr[s0 + j + 2];
        int2 e3 = csr[s0 + j + 3];
        float4 r0 = *(const float4*)&T[(size_t)e0.x * D + c];
        float4 r1 = *(const float4*)&T[(size_t)e1.x * D + c];
        float4 r2 = *(const float4*)&T[(size_t)e2.x * D + c];
        float4 r3 = *(const float4*)&T[(size_t)e3.x * D + c];
        float w0 = __int_as_float(e0.y), w1 = __int_as_float(e1.y);
        float w2 = __int_as_float(e2.y), w3 = __int_as_float(e3.y);
        acc.x = fmaf(w0, r0.x, acc.x); acc.y = fmaf(w0, r0.y, acc.y);
        acc.z = fmaf(w0, r0.z, acc.z); acc.w = fmaf(w0, r0.w, acc.w);
        acc.x = fmaf(w1, r1.x, acc.x); acc.y = fmaf(w1, r1.y, acc.y);
        acc.z = fmaf(w1, r1.z, acc.z); acc.w = fmaf(w1, r1.w, acc.w);
        acc.x = fmaf(w2, r2.x, acc.x); acc.y = fmaf(w2, r2.y, acc.y);
        acc.z = fmaf(w2, r2.z, acc.z); acc.w = fmaf(w2, r2.w, acc.w);
        acc.x = fmaf(w3, r3.x, acc.x); acc.y = fmaf(w3, r3.y, acc.y);
        acc.z = fmaf(w3, r3.z, acc.z); acc.w = fmaf(w3, r3.w, acc.w);
    }
    for (; j < cnt; ++j) {
        int2 e = csr[s0 + j];
        float4 r = *(const float4*)&T[(size_t)e.x * D + c];
        float w = __int_as_float(e.y);
        acc.x = fmaf(w, r.x, acc.x); acc.y = fmaf(w, r.y, acc.y);
        acc.z = fmaf(w, r.z, acc.z); acc.w = fmaf(w, r.w, acc.w);
    }
    if (relu) {
        acc.x = fmaxf(acc.x, 0.f); acc.y = fmaxf(acc.y, 0.f);
        acc.z = fmaxf(acc.z, 0.f); acc.w = fmaxf(acc.w, 0.f);
    }
    *(float4*)&Hout[(size_t)node * D + c] = acc;
}

// ---------------- output GEMM: Out[M,16] = A[M,128] @ Wo[128,16] ----------------

__global__ __launch_bounds__(256) void k_gemm_out(const float* __restrict__ A,
                                                  const float* __restrict__ Wo,
                                                  float* __restrict__ Out, int M) {
    __shared__ float sW[128 * 16];
    for (int i = threadIdx.x * 4; i < 2048; i += 1024)
        *(float4*)&sW[i] = *(const float4*)&Wo[i];
    __syncthreads();
    int r = blockIdx.x * 16 + (threadIdx.x >> 4);
    int c = threadIdx.x & 15;
    if (r >= M) return;
    const float* arow = A + (size_t)r * D;
    float acc = 0.f;
#pragma unroll
    for (int k4 = 0; k4 < 32; ++k4) {
        float4 h = *(const float4*)&arow[k4 * 4];
        acc = fmaf(h.x, sW[(k4 * 4 + 0) * 16 + c], acc);
        acc = fmaf(h.y, sW[(k4 * 4 + 1) * 16 + c], acc);
        acc = fmaf(h.z, sW[(k4 * 4 + 2) * 16 + c], acc);
        acc = fmaf(h.w, sW[(k4 * 4 + 3) * 16 + c], acc);
    }
    Out[(size_t)r * 16 + c] = acc;
}

__global__ __launch_bounds__(256) void k_aggr_out(const float* __restrict__ T16,
                                                  const int2* __restrict__ csr,
                                                  const int* __restrict__ rowst,
                                                  const int* __restrict__ deg,
                                                  const float* __restrict__ dinv,
                                                  const float* __restrict__ bias,
                                                  float* __restrict__ Out, int N) {
    int node = blockIdx.x * 16 + (threadIdx.x >> 4);
    int c = threadIdx.x & 15;
    if (node >= N) return;
    float di = dinv[node];
    float acc = fmaf(di * di, T16[(size_t)node * 16 + c], bias[c]);
    int s0 = rowst[node];
    int cnt = deg[node];
    int j = 0;
    for (; j + 2 <= cnt; j += 2) {
        int2 e0 = csr[s0 + j];
        int2 e1 = csr[s0 + j + 1];
        float r0 = T16[(size_t)e0.x * 16 + c];
        float r1 = T16[(size_t)e1.x * 16 + c];
        acc = fmaf(__int_as_float(e0.y), r0, acc);
        acc = fmaf(__int_as_float(e1.y), r1, acc);
    }
    if (j < cnt) {
        int2 e = csr[s0 + j];
        acc = fmaf(__int_as_float(e.y), T16[(size_t)e.x * 16 + c], acc);
    }
    Out[(size_t)node * 16 + c] = acc;
}

// ---------------- launch ----------------

extern "C" void kernel_launch(void* const* d_in, const int* in_sizes, int n_in,
                              void* d_out, int out_size, void* d_ws, size_t ws_size,
                              hipStream_t stream) {
    const float* x  = (const float*)d_in[0];
    const int*   ei = (const int*)d_in[1];
    const float* Ws = (const float*)d_in[2];
    const float* bs = (const float*)d_in[3];
    const float* Wo = (const float*)d_in[4];
    const float* bo = (const float*)d_in[5];
    float* out = (float*)d_out;

    const int N = in_sizes[0] / D;     // 100000
    const int E = in_sizes[1] / 2;     // 600000
    const int* src = ei;
    const int* dst = ei + E;

    // workspace layout (~109 MB); csr is 8-byte aligned
    float* H      = (float*)d_ws;
    float* T      = H + (size_t)N * D;
    int*   deg    = (int*)(T + (size_t)N * D);
    int*   cursor = deg + N;
    int*   rowst  = cursor + N;
    float* dinv   = (float*)(rowst + N);
    int*   bsums  = (int*)(dinv + N);
    int2*  csr    = (int2*)(bsums + 1024);

    const int NB = (N + 1023) / 1024;

    hipMemsetAsync(deg, 0, (size_t)2 * N * sizeof(int), stream);  // deg + cursor
    k_count<<<(E + 255) / 256, 256, 0, stream>>>(dst, deg, E);
    k_blocksum<<<NB, 256, 0, stream>>>(deg, bsums, N);
    k_scanbsums<<<1, 256, 0, stream>>>(bsums, NB);
    k_scan2<<<NB, 256, 0, stream>>>(deg, bsums, rowst, dinv, N);
    k_fill<<<(E + 255) / 256, 256, 0, stream>>>(src, dst, rowst, cursor, dinv, csr, E);

    const float* hin = x;
    for (int l = 0; l < 9; ++l) {
        k_gemm128<<<(N + 31) / 32, 256, 0, stream>>>(hin, Ws + (size_t)l * D * D, T, N);
        k_aggr<<<(N + 7) / 8, 256, 0, stream>>>(T, csr, rowst, deg, dinv,
                                                bs + (size_t)l * D, H, N, 1);
        hin = H;
    }
    k_gemm_out<<<(N + 15) / 16, 256, 0, stream>>>(H, Wo, T, N);
    k_aggr_out<<<(N + 15) / 16, 256, 0, stream>>>(T, csr, rowst, deg, dinv, bo, out, N);
}